// Round 9
// baseline (15.911 us; speedup 1.0000x reference)
//
#include <hip/hip_runtime.h>
#include <cfloat>

// TripletSemiHardLoss — B=512, D=128, scalar f32 out.
// R9: 3-kernel pipeline killing the 256x embedding re-read:
//  K1 gram: 256 blocks x 256 thr, 32x32 dist tile per block, LDS-staged
//           row/col panels (32 KB/block; total L2 traffic 8 MB vs 67 MB).
//           dist = max(2-2*dot,0) (unit-norm rows), diag zeroed. -> ws (1 MB)
//  K2 mine: 64 blocks x 8 waves, ONE WAVE PER ANCHOR; reads its 2 KB row;
//           in-register ballot mining; reductions end with readlane+v_min
//           (uniform result, no ds_swizzle tail).
//  K3 fin:  1 wave over 64 block partials (fixed order, deterministic).
// Fallback (ws too small): proven R6 two-kernel path.

constexpr int   BN       = 512;
constexpr int   DD       = 128;
constexpr float MARGIN_F = 0.1f;
constexpr int   NBLK     = BN / 2;   // fallback: 256 blocks, 2 anchors each

// ---------------- DPP helpers ----------------
template <int CTRL>
__device__ inline float dppAdd(float v) {
    int x = __builtin_amdgcn_update_dpp(__float_as_int(v), __float_as_int(v),
                                        CTRL, 0xF, 0xF, false);
    return v + __int_as_float(x);
}
template <int CTRL>
__device__ inline float dppMin(float v) {
    int x = __builtin_amdgcn_update_dpp(__float_as_int(v), __float_as_int(v),
                                        CTRL, 0xF, 0xF, false);
    return fminf(v, __int_as_float(x));
}
template <int CTRL>
__device__ inline float dppMax(float v) {
    int x = __builtin_amdgcn_update_dpp(__float_as_int(v), __float_as_int(v),
                                        CTRL, 0xF, 0xF, false);
    return fmaxf(v, __int_as_float(x));
}
constexpr int DPP_XOR1 = 0xB1;   // quad_perm [1,0,3,2]
constexpr int DPP_XOR2 = 0x4E;   // quad_perm [2,3,0,1]
constexpr int DPP_ROR4 = 0x124;  // row_ror:4
constexpr int DPP_ROR8 = 0x128;  // row_ror:8

__device__ inline float rdlane(float v, int l) {
    return __int_as_float(__builtin_amdgcn_readlane(__float_as_int(v), l));
}
// fast wave-min/max: 4 DPP (VALU) + 4 readlane + 3 min — result UNIFORM
__device__ inline float waveMinU(float v) {
    v = dppMin<DPP_XOR1>(v);
    v = dppMin<DPP_XOR2>(v);
    v = dppMin<DPP_ROR4>(v);
    v = dppMin<DPP_ROR8>(v);        // each 16-lane row holds row-min
    return fminf(fminf(rdlane(v, 0), rdlane(v, 16)),
                 fminf(rdlane(v, 32), rdlane(v, 48)));
}
__device__ inline float waveMaxU(float v) {
    v = dppMax<DPP_XOR1>(v);
    v = dppMax<DPP_XOR2>(v);
    v = dppMax<DPP_ROR4>(v);
    v = dppMax<DPP_ROR8>(v);
    return fmaxf(fmaxf(rdlane(v, 0), rdlane(v, 16)),
                 fmaxf(rdlane(v, 32), rdlane(v, 48)));
}
// fallback (R6) variants
__device__ inline float waveMin64(float v) {
    v = dppMin<DPP_XOR1>(v);
    v = dppMin<DPP_XOR2>(v);
    v = dppMin<DPP_ROR4>(v);
    v = dppMin<DPP_ROR8>(v);
    v = fminf(v, __shfl_xor(v, 16, 64));
    v = fminf(v, __shfl_xor(v, 32, 64));
    return v;
}
__device__ inline float waveMax64(float v) {
    v = dppMax<DPP_XOR1>(v);
    v = dppMax<DPP_XOR2>(v);
    v = dppMax<DPP_ROR4>(v);
    v = dppMax<DPP_ROR8>(v);
    v = fmaxf(v, __shfl_xor(v, 16, 64));
    v = fmaxf(v, __shfl_xor(v, 32, 64));
    return v;
}

// ================= K1: tiled Gram -> dist matrix =================
__global__ __launch_bounds__(256) void gram_k(
    const float* __restrict__ emb, float* __restrict__ dist)
{
    __shared__ __align__(16) float rows[32][132];   // +4 floats pad
    __shared__ __align__(16) float cols[32][132];

    const int t  = threadIdx.x;
    const int ti = blockIdx.x >> 4;
    const int tj = blockIdx.x & 15;

    // stage 32-row panels (16 KB each), coalesced float4
    const float4* embv = reinterpret_cast<const float4*>(emb);
#pragma unroll
    for (int i = 0; i < 4; ++i) {
        const int gi = t + i * 256;         // 0..1023
        const int r  = gi >> 5;             // 0..31
        const int q  = gi & 31;             // float4 idx in row
        *reinterpret_cast<float4*>(&rows[r][q * 4]) = embv[(ti * 32 + r) * 32 + q];
        *reinterpret_cast<float4*>(&cols[r][q * 4]) = embv[(tj * 32 + r) * 32 + q];
    }
    __syncthreads();

    const int c  = t & 31;    // col within tile
    const int rq = t >> 5;    // row quartet 0..7
    float acc0 = 0.f, acc1 = 0.f, acc2 = 0.f, acc3 = 0.f;
    const float* colp = &cols[c][0];
    const float* r0p  = &rows[rq * 4 + 0][0];
    const float* r1p  = &rows[rq * 4 + 1][0];
    const float* r2p  = &rows[rq * 4 + 2][0];
    const float* r3p  = &rows[rq * 4 + 3][0];
#pragma unroll
    for (int q = 0; q < 32; ++q) {
        const float4 b  = *reinterpret_cast<const float4*>(colp + q * 4);
        const float4 a0 = *reinterpret_cast<const float4*>(r0p + q * 4);
        const float4 a1 = *reinterpret_cast<const float4*>(r1p + q * 4);
        const float4 a2 = *reinterpret_cast<const float4*>(r2p + q * 4);
        const float4 a3 = *reinterpret_cast<const float4*>(r3p + q * 4);
        acc0 += a0.x * b.x + a0.y * b.y + a0.z * b.z + a0.w * b.w;
        acc1 += a1.x * b.x + a1.y * b.y + a1.z * b.z + a1.w * b.w;
        acc2 += a2.x * b.x + a2.y * b.y + a2.z * b.z + a2.w * b.w;
        acc3 += a3.x * b.x + a3.y * b.y + a3.z * b.z + a3.w * b.w;
    }
    const int cg = tj * 32 + c;
    const float acc[4] = {acc0, acc1, acc2, acc3};
#pragma unroll
    for (int rr = 0; rr < 4; ++rr) {
        const int r = ti * 32 + rq * 4 + rr;
        float d = fmaxf(2.f - 2.f * acc[rr], 0.f);   // unit-norm rows
        if (r == cg) d = 0.f;                        // zero diagonal
        dist[r * BN + cg] = d;
    }
}

// ================= K2: wave-per-anchor mining =================
__global__ __launch_bounds__(512) void mine_k(
    const float* __restrict__ dist, const int* __restrict__ labels,
    float* __restrict__ loss_blk, int* __restrict__ cnt_blk)
{
    __shared__ float ws8[8];
    __shared__ int   wc8[8];

    const int t    = threadIdx.x;
    const int w    = t >> 6;
    const int lane = t & 63;
    const int A    = blockIdx.x * 8 + w;     // anchor for this wave

    const float4* dv  = reinterpret_cast<const float4*>(dist + (size_t)A * BN)
                        + lane * 2;
    const float4  dA4 = dv[0], dB4 = dv[1];
    const int4*   lv  = reinterpret_cast<const int4*>(labels) + lane * 2;
    const int4    lA4 = lv[0], lB4 = lv[1];
    const float ddv[8] = {dA4.x, dA4.y, dA4.z, dA4.w, dB4.x, dB4.y, dB4.z, dB4.w};
    const int   llv[8] = {lA4.x, lA4.y, lA4.z, lA4.w, lB4.x, lB4.y, lB4.z, lB4.w};
    const int   labA   = labels[A];

    float dn[8];
    float nmax = 0.f;
#pragma unroll
    for (int q = 0; q < 8; ++q) {
        const bool neg = (llv[q] != labA);
        dn[q] = neg ? ddv[q] : FLT_MAX;
        nmax  = neg ? fmaxf(nmax, ddv[q]) : nmax;
    }
    const float neg_inside = waveMaxU(nmax);   // uniform

    int   npos = 0;
    float wsum = 0.f;
#pragma unroll
    for (int q = 0; q < 8; ++q) {
        unsigned long long m = __ballot((llv[q] == labA) && (lane * 8 + q != A));
        npos += __popcll(m);
        while (m) {
            const int src = __ffsll((long long)m) - 1;   // wave-uniform
            m &= m - 1;
            const float dpos = rdlane(ddv[q], src);      // uniform broadcast
            float mn = FLT_MAX;
#pragma unroll
            for (int qq = 0; qq < 8; ++qq)
                mn = fminf(mn, (dn[qq] > dpos) ? dn[qq] : FLT_MAX);
            mn = waveMinU(mn);                           // uniform
            const float shn = (mn < FLT_MAX) ? mn : neg_inside;
            wsum += fmaxf(MARGIN_F + dpos - shn, 0.f);   // uniform on all lanes
        }
    }
    if (lane == 0) { ws8[w] = wsum; wc8[w] = npos; }
    __syncthreads();
    if (t == 0) {
        loss_blk[blockIdx.x] = ((ws8[0] + ws8[1]) + (ws8[2] + ws8[3]))
                             + ((ws8[4] + ws8[5]) + (ws8[6] + ws8[7]));
        cnt_blk[blockIdx.x]  = ((wc8[0] + wc8[1]) + (wc8[2] + wc8[3]))
                             + ((wc8[4] + wc8[5]) + (wc8[6] + wc8[7]));
    }
}

// ================= K3: 64-partial finalize =================
__global__ __launch_bounds__(64) void fin64_k(
    const float* __restrict__ loss_blk, const int* __restrict__ cnt_blk,
    float* __restrict__ out)
{
    const int t = threadIdx.x;
    float s = loss_blk[t];
    int   c = cnt_blk[t];
#pragma unroll
    for (int o = 1; o < 64; o <<= 1) {
        s += __shfl_xor(s, o, 64);
        c += __shfl_xor(c, o, 64);
    }
    if (t == 0) out[0] = s / (float)c;
}

// ================= Fallback: proven R6 path =================
__global__ __launch_bounds__(512) void triplet_anchor(
    const float* __restrict__ emb, const int* __restrict__ labels,
    float* __restrict__ loss_part, int* __restrict__ cnt_part)
{
    __shared__ __align__(16) float ej0[DD];
    __shared__ __align__(16) float ej1[DD];
    __shared__ __align__(16) float dist0[BN];
    __shared__ __align__(16) float dist1[BN];
    __shared__ float wsum8[8];

    const int t    = threadIdx.x;
    const int w    = t >> 6;
    const int lane = t & 63;
    const int sub  = t & 3;
    const int a0   = blockIdx.x * 2;
    const int a1   = a0 + 1;

    if (t < DD)          ej0[t]      = emb[(size_t)a0 * DD + t];
    else if (t < 2 * DD) ej1[t - DD] = emb[(size_t)a1 * DD + (t - DD)];
    __syncthreads();

    float4 e0q[8], e1q[8];
    {
        const float4* ej0v = reinterpret_cast<const float4*>(ej0);
        const float4* ej1v = reinterpret_cast<const float4*>(ej1);
#pragma unroll
        for (int qq = 0; qq < 8; ++qq) {
            e0q[qq] = ej0v[qq * 4 + sub];
            e1q[qq] = ej1v[qq * 4 + sub];
        }
    }

    const int rbase = t >> 2;
#pragma unroll 2
    for (int pass = 0; pass < 4; ++pass) {
        const int r = pass * 128 + rbase;
        const float4* rowv = reinterpret_cast<const float4*>(emb + (size_t)r * DD);
        float d0 = 0.f, d1 = 0.f;
#pragma unroll
        for (int qq = 0; qq < 8; ++qq) {
            const float4 b = rowv[qq * 4 + sub];
            const float4 A = e0q[qq], C = e1q[qq];
            d0 += A.x * b.x + A.y * b.y + A.z * b.z + A.w * b.w;
            d1 += C.x * b.x + C.y * b.y + C.z * b.z + C.w * b.w;
        }
        d0 = dppAdd<DPP_XOR1>(d0);
        d0 = dppAdd<DPP_XOR2>(d0);
        d1 = dppAdd<DPP_XOR1>(d1);
        d1 = dppAdd<DPP_XOR2>(d1);
        if (sub == 0) {
            const float dd = fmaxf(2.f - 2.f * d0, 0.f);
            dist0[r] = (r == a0) ? 0.f : dd;
        } else if (sub == 1) {
            const float dd = fmaxf(2.f - 2.f * d1, 0.f);
            dist1[r] = (r == a1) ? 0.f : dd;
        }
    }
    __syncthreads();

    const int    A     = (w < 4) ? a0 : a1;
    const int    wi    = w & 3;
    const float* distA = (w < 4) ? dist0 : dist1;

    const float4* dv  = reinterpret_cast<const float4*>(distA) + lane * 2;
    const float4  dA4 = dv[0], dB4 = dv[1];
    const int4*   lv  = reinterpret_cast<const int4*>(labels) + lane * 2;
    const int4    lA4 = lv[0], lB4 = lv[1];
    const float ddv[8] = {dA4.x, dA4.y, dA4.z, dA4.w, dB4.x, dB4.y, dB4.z, dB4.w};
    const int   llv[8] = {lA4.x, lA4.y, lA4.z, lA4.w, lB4.x, lB4.y, lB4.z, lB4.w};
    const int   labA   = labels[A];

    float dn[8];
    float nmax = 0.f;
#pragma unroll
    for (int q = 0; q < 8; ++q) {
        const bool neg = (llv[q] != labA);
        dn[q] = neg ? ddv[q] : FLT_MAX;
        nmax  = neg ? fmaxf(nmax, ddv[q]) : nmax;
    }
    const float neg_inside = waveMax64(nmax);

    int   npos = 0;
    int   p    = 0;
    float wsum = 0.f;
#pragma unroll
    for (int q = 0; q < 8; ++q) {
        unsigned long long m = __ballot((llv[q] == labA) && (lane * 8 + q != A));
        npos += __popcll(m);
        while (m) {
            const int src = __ffsll((long long)m) - 1;
            m &= m - 1;
            if ((p & 3) == wi) {
                const float dpos = __shfl(ddv[q], src, 64);
                float mn = FLT_MAX;
#pragma unroll
                for (int qq = 0; qq < 8; ++qq)
                    mn = fminf(mn, (dn[qq] > dpos) ? dn[qq] : FLT_MAX);
                mn = waveMin64(mn);
                const float shn = (mn < FLT_MAX) ? mn : neg_inside;
                wsum += fmaxf(MARGIN_F + dpos - shn, 0.f);
            }
            ++p;
        }
    }
    if (lane == 0) wsum8[w] = wsum;
    if (lane == 1 && (w == 0 || w == 4)) cnt_part[A] = npos;
    __syncthreads();
    if (t == 0) loss_part[a0] = (wsum8[0] + wsum8[1]) + (wsum8[2] + wsum8[3]);
    if (t == 1) loss_part[a1] = (wsum8[4] + wsum8[5]) + (wsum8[6] + wsum8[7]);
}

__global__ __launch_bounds__(64) void triplet_finalize(
    const float* __restrict__ loss_part, const int* __restrict__ cnt_part,
    float* __restrict__ out)
{
    const int t = threadIdx.x;
    const float4* lp = reinterpret_cast<const float4*>(loss_part);
    const int4*   cp = reinterpret_cast<const int4*>(cnt_part);
    const float4 s0 = lp[t], s1 = lp[t + 64];
    const int4   c0 = cp[t], c1 = cp[t + 64];
    float s = ((s0.x + s0.y) + (s0.z + s0.w)) + ((s1.x + s1.y) + (s1.z + s1.w));
    int   c = (c0.x + c0.y + c0.z + c0.w) + (c1.x + c1.y + c1.z + c1.w);
#pragma unroll
    for (int o = 1; o < 64; o <<= 1) {
        s += __shfl_xor(s, o, 64);
        c += __shfl_xor(c, o, 64);
    }
    if (t == 0) out[0] = s / (float)c;
}

extern "C" void kernel_launch(void* const* d_in, const int* in_sizes, int n_in,
                              void* d_out, int out_size, void* d_ws, size_t ws_size,
                              hipStream_t stream)
{
    const float* emb    = (const float*)d_in[0];
    const int*   labels = (const int*)d_in[1];
    float*       out    = (float*)d_out;

    const size_t need = (size_t)BN * BN * sizeof(float) + 64 * (sizeof(float) + sizeof(int));
    if (ws_size >= need) {
        float* dist     = (float*)d_ws;
        float* loss_blk = (float*)((char*)d_ws + (size_t)BN * BN * sizeof(float));
        int*   cnt_blk  = (int*)((char*)loss_blk + 64 * sizeof(float));

        gram_k<<<256, 256, 0, stream>>>(emb, dist);
        mine_k<<<64, 512, 0, stream>>>(dist, labels, loss_blk, cnt_blk);
        fin64_k<<<1, 64, 0, stream>>>(loss_blk, cnt_blk, out);
    } else {
        float* loss_part = (float*)d_ws;
        int*   cnt_part  = (int*)((char*)d_ws + BN * sizeof(float));
        triplet_anchor<<<NBLK, 512, 0, stream>>>(emb, labels, loss_part, cnt_part);
        triplet_finalize<<<1, 64, 0, stream>>>(loss_part, cnt_part, out);
    }
}

// Round 10
// 13.329 us; speedup vs baseline: 1.1937x; 1.1937x over previous
//
#include <hip/hip_runtime.h>
#include <cfloat>

// TripletSemiHardLoss — B=512, D=128, scalar f32 out.
// R10: micro-trimmed R6 (best at 13.35us). Two dispatches is measured-optimal
// (R7 1-dispatch tail +4us; R9 3-dispatch +2.5us/node).
//  - anchor frags direct from global (L1 broadcast; ej-stage + barrier gone)
//  - dot: 4 passes x 128 rows, 4 lanes/row, DPP quad_perm add (VALU pipe)
//  - mining: ballot in-register; readlane-tail UNIFORM min/max (no ds_swizzle)
//  - one partial per block (fixed-order L0+L1); finalize = 1 wave, float4.

constexpr int   BN       = 512;
constexpr int   DD       = 128;
constexpr float MARGIN_F = 0.1f;
constexpr int   NBLK     = BN / 2;   // 256 blocks, 2 anchors each

template <int CTRL>
__device__ inline float dppAdd(float v) {
    int x = __builtin_amdgcn_update_dpp(__float_as_int(v), __float_as_int(v),
                                        CTRL, 0xF, 0xF, false);
    return v + __int_as_float(x);
}
template <int CTRL>
__device__ inline float dppMin(float v) {
    int x = __builtin_amdgcn_update_dpp(__float_as_int(v), __float_as_int(v),
                                        CTRL, 0xF, 0xF, false);
    return fminf(v, __int_as_float(x));
}
template <int CTRL>
__device__ inline float dppMax(float v) {
    int x = __builtin_amdgcn_update_dpp(__float_as_int(v), __float_as_int(v),
                                        CTRL, 0xF, 0xF, false);
    return fmaxf(v, __int_as_float(x));
}
constexpr int DPP_XOR1 = 0xB1;   // quad_perm [1,0,3,2]
constexpr int DPP_XOR2 = 0x4E;   // quad_perm [2,3,0,1]
constexpr int DPP_ROR4 = 0x124;  // row_ror:4
constexpr int DPP_ROR8 = 0x128;  // row_ror:8

__device__ inline float rdlane(float v, int l) {
    return __int_as_float(__builtin_amdgcn_readlane(__float_as_int(v), l));
}
// wave min/max: 4 DPP (VALU) + 4 readlane + 3 ops — result UNIFORM, no ds ops
__device__ inline float waveMinU(float v) {
    v = dppMin<DPP_XOR1>(v);
    v = dppMin<DPP_XOR2>(v);
    v = dppMin<DPP_ROR4>(v);
    v = dppMin<DPP_ROR8>(v);        // each 16-lane row holds its row-min
    return fminf(fminf(rdlane(v, 0), rdlane(v, 16)),
                 fminf(rdlane(v, 32), rdlane(v, 48)));
}
__device__ inline float waveMaxU(float v) {
    v = dppMax<DPP_XOR1>(v);
    v = dppMax<DPP_XOR2>(v);
    v = dppMax<DPP_ROR4>(v);
    v = dppMax<DPP_ROR8>(v);
    return fmaxf(fmaxf(rdlane(v, 0), rdlane(v, 16)),
                 fmaxf(rdlane(v, 32), rdlane(v, 48)));
}

__global__ __launch_bounds__(512) void triplet_anchor(
    const float* __restrict__ emb, const int* __restrict__ labels,
    float* __restrict__ loss_blk, int* __restrict__ cnt_blk)
{
    __shared__ __align__(16) float dist0[BN];
    __shared__ __align__(16) float dist1[BN];
    __shared__ float wsum8[8];
    __shared__ int   nposs[2];

    const int t    = threadIdx.x;
    const int w    = t >> 6;
    const int lane = t & 63;
    const int sub  = t & 3;      // 4 lanes per row
    const int a0   = blockIdx.x * 2;
    const int a1   = a0 + 1;

    // anchor fragments direct from global (1 KB, L1 broadcast)
    float4 e0q[8], e1q[8];
    {
        const float4* e0v = reinterpret_cast<const float4*>(emb + (size_t)a0 * DD);
        const float4* e1v = reinterpret_cast<const float4*>(emb + (size_t)a1 * DD);
#pragma unroll
        for (int qq = 0; qq < 8; ++qq) {
            e0q[qq] = e0v[qq * 4 + sub];
            e1q[qq] = e1v[qq * 4 + sub];
        }
    }

    // dot pass: 4 passes x 128 rows, 4 lanes per row (64B/quad contiguous)
    const int rbase = t >> 2;    // 0..127
#pragma unroll 2
    for (int pass = 0; pass < 4; ++pass) {
        const int r = pass * 128 + rbase;
        const float4* rowv = reinterpret_cast<const float4*>(emb + (size_t)r * DD);
        float d0 = 0.f, d1 = 0.f;
#pragma unroll
        for (int qq = 0; qq < 8; ++qq) {
            const float4 b = rowv[qq * 4 + sub];
            const float4 A = e0q[qq], C = e1q[qq];
            d0 += A.x * b.x + A.y * b.y + A.z * b.z + A.w * b.w;
            d1 += C.x * b.x + C.y * b.y + C.z * b.z + C.w * b.w;
        }
        d0 = dppAdd<DPP_XOR1>(d0);
        d0 = dppAdd<DPP_XOR2>(d0);
        d1 = dppAdd<DPP_XOR1>(d1);
        d1 = dppAdd<DPP_XOR2>(d1);
        // unit-norm rows: dist = max(2 - 2*dot, 0); zero diagonal inline
        if (sub == 0) {
            const float dd = fmaxf(2.f - 2.f * d0, 0.f);
            dist0[r] = (r == a0) ? 0.f : dd;
        } else if (sub == 1) {
            const float dd = fmaxf(2.f - 2.f * d1, 0.f);
            dist1[r] = (r == a1) ? 0.f : dd;
        }
    }
    __syncthreads();

    // --- mining: waves 0-3 -> anchor a0, waves 4-7 -> anchor a1 ---
    const int    A     = (w < 4) ? a0 : a1;
    const int    wi    = w & 3;
    const float* distA = (w < 4) ? dist0 : dist1;

    const float4* dv  = reinterpret_cast<const float4*>(distA) + lane * 2;
    const float4  dA4 = dv[0], dB4 = dv[1];
    const int4*   lv  = reinterpret_cast<const int4*>(labels) + lane * 2;
    const int4    lA4 = lv[0], lB4 = lv[1];
    const float ddv[8] = {dA4.x, dA4.y, dA4.z, dA4.w, dB4.x, dB4.y, dB4.z, dB4.w};
    const int   llv[8] = {lA4.x, lA4.y, lA4.z, lA4.w, lB4.x, lB4.y, lB4.z, lB4.w};
    const int   labA   = labels[A];

    float dn[8];
    float nmax = 0.f;
#pragma unroll
    for (int q = 0; q < 8; ++q) {
        const bool neg = (llv[q] != labA);
        dn[q] = neg ? ddv[q] : FLT_MAX;
        nmax  = neg ? fmaxf(nmax, ddv[q]) : nmax;
    }
    const float neg_inside = waveMaxU(nmax);   // uniform

    int   npos = 0;
    int   p    = 0;
    float wsum = 0.f;                           // uniform accumulator
#pragma unroll
    for (int q = 0; q < 8; ++q) {
        unsigned long long m = __ballot((llv[q] == labA) && (lane * 8 + q != A));
        npos += __popcll(m);
        while (m) {
            const int src = __ffsll((long long)m) - 1;   // wave-uniform
            m &= m - 1;
            if ((p & 3) == wi) {
                const float dpos = rdlane(ddv[q], src);  // uniform broadcast
                float mn = FLT_MAX;
#pragma unroll
                for (int qq = 0; qq < 8; ++qq)
                    mn = fminf(mn, (dn[qq] > dpos) ? dn[qq] : FLT_MAX);
                mn = waveMinU(mn);                       // uniform
                const float shn = (mn < FLT_MAX) ? mn : neg_inside;
                wsum += fmaxf(MARGIN_F + dpos - shn, 0.f);
            }
            ++p;
        }
    }
    if (lane == 0) wsum8[w] = wsum;
    if (lane == 1 && w == 0) nposs[0] = npos;
    if (lane == 1 && w == 4) nposs[1] = npos;
    __syncthreads();
    if (t == 0) {
        const float L0 = (wsum8[0] + wsum8[1]) + (wsum8[2] + wsum8[3]);
        const float L1 = (wsum8[4] + wsum8[5]) + (wsum8[6] + wsum8[7]);
        loss_blk[blockIdx.x] = L0 + L1;
        cnt_blk[blockIdx.x]  = nposs[0] + nposs[1];
    }
}

__global__ __launch_bounds__(64) void triplet_finalize(
    const float* __restrict__ loss_blk, const int* __restrict__ cnt_blk,
    float* __restrict__ out)
{
    const int t = threadIdx.x;   // one wave, 256 partials as float4/int4
    const float4 s4 = reinterpret_cast<const float4*>(loss_blk)[t];
    const int4   c4 = reinterpret_cast<const int4*>(cnt_blk)[t];
    float s = (s4.x + s4.y) + (s4.z + s4.w);
    int   c = (c4.x + c4.y) + (c4.z + c4.w);
#pragma unroll
    for (int o = 1; o < 64; o <<= 1) {
        s += __shfl_xor(s, o, 64);
        c += __shfl_xor(c, o, 64);
    }
    if (t == 0) out[0] = s / (float)c;
}

extern "C" void kernel_launch(void* const* d_in, const int* in_sizes, int n_in,
                              void* d_out, int out_size, void* d_ws, size_t ws_size,
                              hipStream_t stream)
{
    const float* emb    = (const float*)d_in[0];
    const int*   labels = (const int*)d_in[1];
    float*       out    = (float*)d_out;

    float* loss_blk = (float*)d_ws;
    int*   cnt_blk  = (int*)((char*)d_ws + NBLK * sizeof(float));

    triplet_anchor<<<NBLK, 512, 0, stream>>>(emb, labels, loss_blk, cnt_blk);
    triplet_finalize<<<1, 64, 0, stream>>>(loss_blk, cnt_blk, out);
}